// Round 4
// baseline (57.227 us; speedup 1.0000x reference)
//
#include <hip/hip_runtime.h>
#include <math.h>

#define NSLOT 5
#define NBUF 3
#define EPSF 1e-8f

typedef float f4 __attribute__((ext_vector_type(4)));

// One wave (64 threads) per sample. D=2048 -> n4=512 f4 chunks -> 8 per lane.
template<int N4>
__global__ __launch_bounds__(64, 4) void mb_kernel(
    const float* __restrict__ query,    // B x D
    const int*   __restrict__ labels,   // B
    const float* __restrict__ mkeys,    // C x S x D
    const float* __restrict__ mvals,    // C x S x D
    const float* __restrict__ qscores,  // C x S
    const int*   __restrict__ topk_p,   // scalar
    float* __restrict__ out_ret,        // B x D
    float* __restrict__ out_w,          // B
    int B, int n4_rt)
{
    const int lane = threadIdx.x;        // 0..63
    const int i    = blockIdx.x;
    if (i >= B) return;
    const int c = labels[i];

    int k = topk_p[0];
    if (k > NSLOT) k = NSLOT;
    if (k < 1) k = 1;

    const int n4 = (N4 > 0) ? N4 : n4_rt;
    const f4* q4 = reinterpret_cast<const f4*>(query) + (size_t)i * n4;
    const f4* k4 = reinterpret_cast<const f4*>(mkeys) + (size_t)c * NSLOT * n4;
    const f4* v4 = reinterpret_cast<const f4*>(mvals) + (size_t)c * NSLOT * n4;
    f4*       o4 = reinterpret_cast<f4*>(out_ret) + (size_t)i * n4;

    float qq = 0.f;
    float dot[NSLOT], kk[NSLOT];
#pragma unroll
    for (int s = 0; s < NSLOT; ++s) { dot[s] = 0.f; kk[s] = 0.f; }

    // ---------------- pass 1: qq, dot[s], kk[s] -----------------
    if constexpr (N4 > 0) {
        constexpr int NCH = N4 / 64;     // 8 chunks
        f4 qb[NBUF];
        f4 kb[NBUF][NSLOT];
        // prologue: fill NBUF buffers (18 loads in flight)
#pragma unroll
        for (int b = 0; b < NBUF; ++b) {
            qb[b] = __builtin_nontemporal_load(&q4[lane + b * 64]);
#pragma unroll
            for (int s = 0; s < NSLOT; ++s)
                kb[b][s] = k4[s * N4 + lane + b * 64];
        }
#pragma unroll
        for (int j = 0; j < NCH; ++j) {
            constexpr int M = NBUF;
            const int b = j % M;         // compile-time after unroll
            f4 q = qb[b];
            f4 kv[NSLOT];
#pragma unroll
            for (int s = 0; s < NSLOT; ++s) kv[s] = kb[b][s];
            if (j + M < NCH) {           // reload this buffer with chunk j+M
                qb[b] = __builtin_nontemporal_load(&q4[lane + (j + M) * 64]);
#pragma unroll
                for (int s = 0; s < NSLOT; ++s)
                    kb[b][s] = k4[s * N4 + lane + (j + M) * 64];
            }
            qq = fmaf(q.x, q.x, fmaf(q.y, q.y, fmaf(q.z, q.z, fmaf(q.w, q.w, qq))));
#pragma unroll
            for (int s = 0; s < NSLOT; ++s) {
                dot[s] = fmaf(q.x, kv[s].x, fmaf(q.y, kv[s].y,
                         fmaf(q.z, kv[s].z, fmaf(q.w, kv[s].w, dot[s]))));
                kk[s]  = fmaf(kv[s].x, kv[s].x, fmaf(kv[s].y, kv[s].y,
                         fmaf(kv[s].z, kv[s].z, fmaf(kv[s].w, kv[s].w, kk[s]))));
            }
        }
    } else {
        for (int idx = lane; idx < n4; idx += 64) {
            f4 q = q4[idx];
            qq = fmaf(q.x, q.x, fmaf(q.y, q.y, fmaf(q.z, q.z, fmaf(q.w, q.w, qq))));
            for (int s = 0; s < NSLOT; ++s) {
                f4 kv = k4[s * n4 + idx];
                dot[s] = fmaf(q.x, kv.x, fmaf(q.y, kv.y, fmaf(q.z, kv.z, fmaf(q.w, kv.w, dot[s]))));
                kk[s]  = fmaf(kv.x, kv.x, fmaf(kv.y, kv.y, fmaf(kv.z, kv.z, fmaf(kv.w, kv.w, kk[s]))));
            }
        }
    }

    // ---------------- butterfly reduce across 64 lanes ----------------
#pragma unroll
    for (int off = 1; off < 64; off <<= 1) {
        qq += __shfl_xor(qq, off);
#pragma unroll
        for (int s = 0; s < NSLOT; ++s) {
            dot[s] += __shfl_xor(dot[s], off);
            kk[s]  += __shfl_xor(kk[s], off);
        }
    }

    // ---------------- scalar epilogue (all lanes redundantly) ----------------
    float qn = fmaxf(sqrtf(qq), EPSF);

    float scores[NSLOT];
    float ssum = 0.f;
#pragma unroll
    for (int s = 0; s < NSLOT; ++s) {
        scores[s] = qscores[(size_t)c * NSLOT + s];
        ssum += scores[s];
    }

    float comb[NSLOT];
#pragma unroll
    for (int s = 0; s < NSLOT; ++s) {
        float kn = fmaxf(sqrtf(kk[s]), EPSF);
        comb[s] = (dot[s] / (qn * kn)) * scores[s];
    }

    // top-k descending; ties -> lowest index (strict > keeps first max)
    bool used[NSLOT];
#pragma unroll
    for (int s = 0; s < NSLOT; ++s) used[s] = false;
    float tsc[NSLOT];
    int   tix[NSLOT];
#pragma unroll
    for (int j = 0; j < NSLOT; ++j) {
        float best = -INFINITY;
        int bi = 0;
        if (j < k) {
#pragma unroll
            for (int s = 0; s < NSLOT; ++s) {
                if (!used[s] && comb[s] > best) { best = comb[s]; bi = s; }
            }
#pragma unroll
            for (int s = 0; s < NSLOT; ++s) used[s] = used[s] || (s == bi);
        }
        tsc[j] = best;
        tix[j] = bi;
    }

    // softmax(top/TEMP), max-subtracted (tsc[0] is the max)
    const bool hit = (ssum != 0.0f);
    float m = tsc[0];
    float esum = 0.f, wsum = 0.f;
    float a[NSLOT];
#pragma unroll
    for (int j = 0; j < NSLOT; ++j) {
        if (j < k) {
            a[j] = __expf((tsc[j] - m) * 10.0f);   // 1/TEMP = 10
            esum += a[j];
            wsum += tsc[j];
        } else {
            a[j] = 0.f;
        }
    }
    float inv = hit ? (1.0f / esum) : 0.0f;        // miss -> zero weights -> zero output

    // per-slot weights (compile-time indexing only; no scratch)
    float w[NSLOT];
#pragma unroll
    for (int s = 0; s < NSLOT; ++s) {
        float ws = 0.f;
#pragma unroll
        for (int j = 0; j < NSLOT; ++j)
            if (j < k && tix[j] == s) ws += a[j] * inv;
        w[s] = ws;
    }

    if (lane == 0) out_w[i] = hit ? (wsum / (float)k) : 0.0f;

    // ---------------- pass 2: out = sum_s w[s] * vals[s] ----------------
    if constexpr (N4 > 0) {
        constexpr int NCH = N4 / 64;
        f4 vb[NBUF][NSLOT];
#pragma unroll
        for (int b = 0; b < NBUF; ++b)
#pragma unroll
            for (int s = 0; s < NSLOT; ++s)
                vb[b][s] = v4[s * N4 + lane + b * 64];
#pragma unroll
        for (int j = 0; j < NCH; ++j) {
            constexpr int M = NBUF;
            const int b = j % M;
            f4 vv[NSLOT];
#pragma unroll
            for (int s = 0; s < NSLOT; ++s) vv[s] = vb[b][s];
            if (j + M < NCH) {
#pragma unroll
                for (int s = 0; s < NSLOT; ++s)
                    vb[b][s] = v4[s * N4 + lane + (j + M) * 64];
            }
            f4 acc = (f4)(0.f);
#pragma unroll
            for (int s = 0; s < NSLOT; ++s) {
                acc.x = fmaf(w[s], vv[s].x, acc.x);
                acc.y = fmaf(w[s], vv[s].y, acc.y);
                acc.z = fmaf(w[s], vv[s].z, acc.z);
                acc.w = fmaf(w[s], vv[s].w, acc.w);
            }
            __builtin_nontemporal_store(acc, &o4[lane + j * 64]);
        }
    } else {
        for (int idx = lane; idx < n4; idx += 64) {
            f4 acc = (f4)(0.f);
            for (int s = 0; s < NSLOT; ++s) {
                f4 v = v4[s * n4 + idx];
                acc.x = fmaf(w[s], v.x, acc.x);
                acc.y = fmaf(w[s], v.y, acc.y);
                acc.z = fmaf(w[s], v.z, acc.z);
                acc.w = fmaf(w[s], v.w, acc.w);
            }
            o4[idx] = acc;
        }
    }
}

extern "C" void kernel_launch(void* const* d_in, const int* in_sizes, int n_in,
                              void* d_out, int out_size, void* d_ws, size_t ws_size,
                              hipStream_t stream) {
    const float* query   = (const float*)d_in[0];
    const int*   labels  = (const int*)d_in[1];
    const float* mkeys   = (const float*)d_in[2];
    const float* mvals   = (const float*)d_in[3];
    const float* qscores = (const float*)d_in[4];
    const int*   topk    = (const int*)d_in[5];

    const int B  = in_sizes[1];
    const int D  = in_sizes[0] / B;
    const int n4 = D >> 2;

    float* out_ret = (float*)d_out;
    float* out_w   = out_ret + (size_t)B * D;

    dim3 grid(B), block(64);
    if (D == 2048) {
        mb_kernel<512><<<grid, block, 0, stream>>>(
            query, labels, mkeys, mvals, qscores, topk, out_ret, out_w, B, n4);
    } else if (D == 1024) {
        mb_kernel<256><<<grid, block, 0, stream>>>(
            query, labels, mkeys, mvals, qscores, topk, out_ret, out_w, B, n4);
    } else {
        mb_kernel<0><<<grid, block, 0, stream>>>(
            query, labels, mkeys, mvals, qscores, topk, out_ret, out_w, B, n4);
    }
}